// Round 7
// baseline (773.360 us; speedup 1.0000x reference)
//
#include <hip/hip_runtime.h>
#include <hip/hip_bf16.h>

typedef __attribute__((ext_vector_type(8))) short bf16x8;
typedef __attribute__((ext_vector_type(4))) float f32x4;

__device__ __forceinline__ float bf2f(short u) {
  union { unsigned int u; float f; } c;
  c.u = ((unsigned int)(unsigned short)u) << 16;
  return c.f;
}
__device__ __forceinline__ short f2bf(float f) {
  union { float f; unsigned int u; } c; c.f = f;
  unsigned int r = (c.u + 0x7fffu + ((c.u >> 16) & 1u)) >> 16;
  return (short)(unsigned short)r;
}

__device__ __forceinline__ void gload16(const void* g, void* l) {
  __builtin_amdgcn_global_load_lds(
      (const __attribute__((address_space(1))) unsigned int*)g,
      (__attribute__((address_space(3))) unsigned int*)l, 16, 0, 0);
}

// ---------------- fp32 -> bf16 convert ----------------
__global__ __launch_bounds__(256) void cvt_k(const float* __restrict__ in,
                                             short* __restrict__ out, int n4) {
  int i = blockIdx.x * blockDim.x + threadIdx.x;
  const int stride = gridDim.x * blockDim.x;
  for (; i < n4; i += stride) {
    float4 v = ((const float4*)in)[i];
    short4 o;
    o.x = f2bf(v.x); o.y = f2bf(v.y); o.z = f2bf(v.z); o.w = f2bf(v.w);
    ((short4*)out)[i] = o;
  }
}

// ---------------- W [1024][1024] f32 -> W^T bf16 ----------------
__global__ __launch_bounds__(256) void cvtT_k(const float* __restrict__ W,
                                              short* __restrict__ Wt) {
  __shared__ float tile[32][33];
  const int n0 = blockIdx.x * 32, k0 = blockIdx.y * 32;
  const int tr = threadIdx.x >> 5;
  const int tc = threadIdx.x & 31;
#pragma unroll
  for (int p = 0; p < 4; ++p)
    tile[p * 8 + tr][tc] = W[(long long)(k0 + p * 8 + tr) * 1024 + n0 + tc];
  __syncthreads();
#pragma unroll
  for (int p = 0; p < 4; ++p)
    Wt[(long long)(n0 + p * 8 + tr) * 1024 + k0 + tc] = f2bf(tile[tc][p * 8 + tr]);
}

// =====================================================================
// 256x128x32 bf16 MFMA GEMM, 2 blocks/CU (48 KiB LDS, VGPR<=128)
//   C[m][n] = sum_k A[m][k] * Bt[n][k]
// 8 waves (4M x 2N), per-wave out 64x64 (acc[4][4] f32x4 = 64 VGPR).
// Per K-tile: RD (8 ds_read_b128) -> lgkmcnt(0) -> barrier ->
//   stage t+2 into just-freed buffer (3 gload16/wave) -> 16 MFMA ->
//   vmcnt(3) -> barrier.  Cross-block overlap hides drains.
// Swizzle (64B rows, 16B slots): slot' = slot ^ (row&3) ^ ((row>>2)&3),
// applied on global source (linear gload_lds dest) AND on ds_read addr.
// XCD-aware bijective grid swizzle (nwg % 8 == 0).
// EPI 0: bf16 out + bias[col]; 1: bf16 out*scale; 2: f32 out + X[idx];
// EPI 3: bf16 out to V^T layout [b][f=row][s], bias[row].
// =====================================================================

template<int EPI>
__global__ __launch_bounds__(512, 4) void gemm8_k(
    const short* __restrict__ A, const short* __restrict__ Bt,
    void* __restrict__ Cv, const float* __restrict__ X,
    int K, int lda, int ldb, int ldc,
    long long strA, long long strB, long long strC, long long strX, float scale) {
  // LDS (shorts): buf0.A @0 (8192), buf1.A @8192, buf0.B @16384 (4096), buf1.B @20480
  __shared__ __align__(16) short Ls[24576];   // 48 KiB

  const int lane = threadIdx.x & 63;
  const int w = threadIdx.x >> 6;       // 0..7
  const int wm = w >> 1, wn = w & 1;
  const int l15 = lane & 15;
  const int g4 = lane >> 4;             // 0..3
  // read-side swizzled 16B-slot (element offset within 32-elem row)
  const int swR = ((g4 ^ (l15 & 3) ^ ((l15 >> 2) & 3)) << 3);
  const int arow = (wm * 64 + l15) * 32 + swR;   // + mi*512
  const int brow = (wn * 64 + l15) * 32 + swR;   // + ni*512
  // stage-side inverse swizzle (lane covers row=lane>>2, slot=lane&3 of a 1KB chunk)
  const int sg = (lane & 3) ^ ((lane >> 2) & 3) ^ ((lane >> 4) & 3);

  // ---- XCD-aware bijective block swizzle (requires nwg % 8 == 0) ----
  const int gx = gridDim.x, gy = gridDim.y;
  const int nwg = gx * gy * gridDim.z;
  int lid = blockIdx.x + gx * (blockIdx.y + gy * blockIdx.z);
  lid = (lid & 7) * (nwg >> 3) + (lid >> 3);
  const int bx = lid % gx;
  const int rem = lid / gx;
  const int by = rem % gy;
  const int bz = rem / gy;

  const int n0 = bx * 128;
  const int m0 = by * 256;
  const int nt = K >> 5;

  const long long ldaB = 2LL * lda, ldbB = 2LL * ldb;
  const long long ldaB16 = 16 * ldaB;

  // per-lane pre-swizzled staging source pointers (dest stays linear)
  const char* pA = (const char*)(A + (long long)bz * strA)
      + (long long)(m0 + w * 32 + (lane >> 2)) * ldaB + sg * 16;
  const char* pB = (const char*)(Bt + (long long)bz * strB)
      + (long long)(n0 + w * 16 + (lane >> 2)) * ldbB + sg * 16;

  short* dA = Ls + w * 1024;            // chunks w*2, w*2+1 (q=0,1); + buf*8192
  short* dB = Ls + 16384 + w * 512;     // chunk w; + buf*4096

  f32x4 acc[4][4] = {};

  // ---- prologue: stage tile0 -> buf0, tile1 -> buf1 ----
  gload16(pA,               dA);
  gload16(pA + ldaB16,      dA + 512);
  gload16(pB,               dB);
  gload16(pA + 64,          dA + 8192);
  gload16(pA + 64 + ldaB16, dA + 8192 + 512);
  gload16(pB + 64,          dB + 4096);
  asm volatile("s_waitcnt vmcnt(3)" ::: "memory");   // tile0 landed
  __builtin_amdgcn_s_barrier();

  for (int t = 0; t < nt; ++t) {
    const int ab = (t & 1) << 13;   // buf select for A (shorts)
    const int bb = (t & 1) << 12;   // buf select for B
    bf16x8 aR[4], bR[4];
#pragma unroll
    for (int mi = 0; mi < 4; ++mi)
      aR[mi] = *(const bf16x8*)(Ls + ab + arow + mi * 512);
#pragma unroll
    for (int ni = 0; ni < 4; ++ni)
      bR[ni] = *(const bf16x8*)(Ls + 16384 + bb + brow + ni * 512);
    asm volatile("s_waitcnt lgkmcnt(0)" ::: "memory");  // my reads done
    __builtin_amdgcn_s_barrier();                       // everyone's done
    if (t + 2 < nt) {                                   // refill freed buffer
      const char* qA = pA + (t + 2) * 64;
      const char* qB = pB + (t + 2) * 64;
      gload16(qA,          dA + ab);
      gload16(qA + ldaB16, dA + ab + 512);
      gload16(qB,          dB + bb);
    }
    __builtin_amdgcn_sched_barrier(0);
    __builtin_amdgcn_s_setprio(1);
#pragma unroll
    for (int mi = 0; mi < 4; ++mi)
#pragma unroll
      for (int ni = 0; ni < 4; ++ni)
        acc[mi][ni] = __builtin_amdgcn_mfma_f32_16x16x32_bf16(
            aR[mi], bR[ni], acc[mi][ni], 0, 0, 0);
    __builtin_amdgcn_s_setprio(0);
    if (t + 2 < nt) asm volatile("s_waitcnt vmcnt(3)" ::: "memory");  // t+1 landed
    else            asm volatile("s_waitcnt vmcnt(0)" ::: "memory");
    __builtin_amdgcn_s_barrier();
  }

  // ---- epilogue ----
  const int rB = g4 * 4;
  if (EPI == 0) {
    short* C = (short*)Cv + (long long)bz * strC;
#pragma unroll
    for (int ni = 0; ni < 4; ++ni) {
      const int col = n0 + wn * 64 + ni * 16 + l15;
      const float bv = X[col];
#pragma unroll
      for (int mi = 0; mi < 4; ++mi)
#pragma unroll
        for (int r = 0; r < 4; ++r) {
          const int row = m0 + wm * 64 + mi * 16 + rB + r;
          C[(long long)row * ldc + col] = f2bf(acc[mi][ni][r] + bv);
        }
    }
  } else if (EPI == 1) {
    short* C = (short*)Cv + (long long)bz * strC;
#pragma unroll
    for (int ni = 0; ni < 4; ++ni) {
      const int col = n0 + wn * 64 + ni * 16 + l15;
#pragma unroll
      for (int mi = 0; mi < 4; ++mi)
#pragma unroll
        for (int r = 0; r < 4; ++r) {
          const int row = m0 + wm * 64 + mi * 16 + rB + r;
          C[(long long)row * ldc + col] = f2bf(acc[mi][ni][r] * scale);
        }
    }
  } else if (EPI == 2) {
    float* C = (float*)Cv + (long long)bz * strC;
    const float* Xb = X + (long long)bz * strX;
#pragma unroll
    for (int ni = 0; ni < 4; ++ni) {
      const int col = n0 + wn * 64 + ni * 16 + l15;
#pragma unroll
      for (int mi = 0; mi < 4; ++mi)
#pragma unroll
        for (int r = 0; r < 4; ++r) {
          const int row = m0 + wm * 64 + mi * 16 + rB + r;
          const long long idx = (long long)row * ldc + col;
          C[idx] = acc[mi][ni][r] + Xb[idx];
        }
    }
  } else {  // EPI == 3: C = V^T, [b][f=row][s], n = b*2048 + s
    short* C = (short*)Cv;
#pragma unroll
    for (int ni = 0; ni < 4; ++ni) {
      const int col = n0 + wn * 64 + ni * 16 + l15;
      const int b2 = col >> 11;
      const int s = col & 2047;
#pragma unroll
      for (int mi = 0; mi < 4; ++mi)
#pragma unroll
        for (int r = 0; r < 4; ++r) {
          const int row = m0 + wm * 64 + mi * 16 + rB + r;
          C[(long long)b2 * 2097152 + (long long)row * 2048 + s] =
              f2bf(acc[mi][ni][r] + X[row]);
        }
    }
  }
}

// ---------------- row softmax over 2048 (in-place, bf16) ----------------
__global__ __launch_bounds__(256) void softmax_k(short* __restrict__ P) {
  __shared__ float redm[4];
  __shared__ float reds[4];
  const long long row = blockIdx.x;
  short* p = P + row * 2048;
  const int t = threadIdx.x;
  const int w = t >> 6, lane = t & 63;
  bf16x8 v = *(const bf16x8*)(p + t * 8);
  float f[8];
  float mx = -3.0e38f;
#pragma unroll
  for (int j = 0; j < 8; ++j) { f[j] = bf2f(v[j]); mx = fmaxf(mx, f[j]); }
#pragma unroll
  for (int o = 32; o > 0; o >>= 1) mx = fmaxf(mx, __shfl_xor(mx, o));
  if (lane == 0) redm[w] = mx;
  __syncthreads();
  mx = fmaxf(fmaxf(redm[0], redm[1]), fmaxf(redm[2], redm[3]));
  float s = 0.f;
#pragma unroll
  for (int j = 0; j < 8; ++j) { f[j] = __expf(f[j] - mx); s += f[j]; }
#pragma unroll
  for (int o = 32; o > 0; o >>= 1) s += __shfl_xor(s, o);
  if (lane == 0) reds[w] = s;
  __syncthreads();
  s = reds[0] + reds[1] + reds[2] + reds[3];
  const float inv = 1.0f / (s + 1e-6f);
  bf16x8 o8;
#pragma unroll
  for (int j = 0; j < 8; ++j) o8[j] = f2bf(f[j] * inv);
  *(bf16x8*)(p + t * 8) = o8;
}

extern "C" void kernel_launch(void* const* d_in, const int* in_sizes, int n_in,
                              void* d_out, int out_size, void* d_ws, size_t ws_size,
                              hipStream_t stream) {
  const float* x  = (const float*)d_in[0];
  const float* y  = (const float*)d_in[1];
  const float* Wq = (const float*)d_in[2];
  const float* bq = (const float*)d_in[3];
  const float* Wk = (const float*)d_in[4];
  const float* bk = (const float*)d_in[5];
  const float* Wv = (const float*)d_in[6];
  const float* bv = (const float*)d_in[7];
  float* out = (float*)d_out;

  const long long SD  = 2048LL * 1024;
  const long long BSD = 16LL * SD;
  const long long SS  = 2048LL * 2048;

  char* ws = (char*)d_ws;
  short* xb  = (short*)ws;                   // 67.1 MB
  short* yb  = xb + BSD;                     // 67.1 MB
  short* Sl  = (short*)ws;                   // 134.2 MB (aliases xb+yb; written after they die)
  short* Qb  = (short*)(ws + 134217728);     // 67.1 MB
  short* Kb  = Qb + BSD;                     // 67.1 MB
  short* Vt  = Kb + BSD;                     // 67.1 MB  [b][d][s]
  short* Wqt = Vt + BSD;                     // 2 MB each
  short* Wkt = Wqt + 1024 * 1024;
  short* Wvt = Wkt + 1024 * 1024;

  // 1) convert x, y to bf16
  cvt_k<<<2048, 256, 0, stream>>>(x, xb, (int)(BSD / 4));
  cvt_k<<<2048, 256, 0, stream>>>(y, yb, (int)(BSD / 4));

  // 2) transpose+convert weights
  cvtT_k<<<dim3(32, 32), 256, 0, stream>>>(Wq, Wqt);
  cvtT_k<<<dim3(32, 32), 256, 0, stream>>>(Wk, Wkt);
  cvtT_k<<<dim3(32, 32), 256, 0, stream>>>(Wv, Wvt);

  // 3) Q = xb @ Wq + bq   (M=32768, N=1024, K=1024)
  gemm8_k<0><<<dim3(8, 128, 1), 512, 0, stream>>>(
      xb, Wqt, Qb, bq, 1024, 1024, 1024, 1024, 0, 0, 0, 0, 1.f);
  // 4) K = yb @ Wk + bk
  gemm8_k<0><<<dim3(8, 128, 1), 512, 0, stream>>>(
      yb, Wkt, Kb, bk, 1024, 1024, 1024, 1024, 0, 0, 0, 0, 1.f);
  // 5) V^T directly: A = Wv^T (M=1024=f), Bt = yb (N=32768) -> Vt[b][f][s]
  gemm8_k<3><<<dim3(256, 4, 1), 512, 0, stream>>>(
      Wvt, yb, Vt, bv, 1024, 1024, 1024, 0, 0, 0, 0, 0, 1.f);

  // 6) logits = Q @ K^T / 32  (batched 16x: M=N=2048, K=1024) -> bf16
  gemm8_k<1><<<dim3(16, 8, 16), 512, 0, stream>>>(
      Qb, Kb, Sl, nullptr, 1024, 1024, 1024, 2048, SD, SD, SS, 0, 0.03125f);

  // 7) softmax rows (32768 rows of 2048), in-place
  softmax_k<<<32768, 256, 0, stream>>>(Sl);

  // 8) out = P @ V + x  (batched 16x: M=2048, N=1024, K=2048) -> f32
  gemm8_k<2><<<dim3(8, 8, 16), 512, 0, stream>>>(
      Sl, Vt, out, x, 2048, 2048, 2048, 1024, SS, SD, SD, SD, 1.f);

  (void)in_sizes; (void)n_in; (void)out_size; (void)ws_size;
}

// Round 8
// 758.200 us; speedup vs baseline: 1.0200x; 1.0200x over previous
//
#include <hip/hip_runtime.h>
#include <hip/hip_bf16.h>

typedef __attribute__((ext_vector_type(8))) short bf16x8;
typedef __attribute__((ext_vector_type(4))) float f32x4;

__device__ __forceinline__ float bf2f(short u) {
  union { unsigned int u; float f; } c;
  c.u = ((unsigned int)(unsigned short)u) << 16;
  return c.f;
}
__device__ __forceinline__ short f2bf(float f) {
  union { float f; unsigned int u; } c; c.f = f;
  unsigned int r = (c.u + 0x7fffu + ((c.u >> 16) & 1u)) >> 16;
  return (short)(unsigned short)r;
}

__device__ __forceinline__ void gload16(const void* g, void* l) {
  __builtin_amdgcn_global_load_lds(
      (const __attribute__((address_space(1))) unsigned int*)g,
      (__attribute__((address_space(3))) unsigned int*)l, 16, 0, 0);
}

// ---------------- fp32 -> bf16 convert ----------------
__global__ __launch_bounds__(256) void cvt_k(const float* __restrict__ in,
                                             short* __restrict__ out, int n4) {
  int i = blockIdx.x * blockDim.x + threadIdx.x;
  const int stride = gridDim.x * blockDim.x;
  for (; i < n4; i += stride) {
    float4 v = ((const float4*)in)[i];
    short4 o;
    o.x = f2bf(v.x); o.y = f2bf(v.y); o.z = f2bf(v.z); o.w = f2bf(v.w);
    ((short4*)out)[i] = o;
  }
}

// ---------------- W [1024][1024] f32 -> W^T bf16 ----------------
__global__ __launch_bounds__(256) void cvtT_k(const float* __restrict__ W,
                                              short* __restrict__ Wt) {
  __shared__ float tile[32][33];
  const int n0 = blockIdx.x * 32, k0 = blockIdx.y * 32;
  const int tr = threadIdx.x >> 5;
  const int tc = threadIdx.x & 31;
#pragma unroll
  for (int p = 0; p < 4; ++p)
    tile[p * 8 + tr][tc] = W[(long long)(k0 + p * 8 + tr) * 1024 + n0 + tc];
  __syncthreads();
#pragma unroll
  for (int p = 0; p < 4; ++p)
    Wt[(long long)(n0 + p * 8 + tr) * 1024 + k0 + tc] = f2bf(tile[tc][p * 8 + tr]);
}

// =====================================================================
// 256x128x32 bf16 MFMA GEMM, TRIPLE-buffered (72 KiB LDS, 2 blocks/CU)
//   C[m][n] = sum_k A[m][k] * Bt[n][k]
// 8 waves (4M x 2N), per-wave out 64x64 (acc[4][4] f32x4 = 64 VGPR).
// Prefetch depth 3 K-tiles: stage t+3 issued at tile t, vmcnt(6) at tile
// end enforces only "t+1 landed" -> each load gets ~2 K-tile-times
// (>> 900cyc HBM latency) to complete; 6KB/wave in flight.
// Swizzle (64B rows, 4x16B slots): LDS[r][s] = global[r][s ^ ((r>>1)&3)].
//   stage source slot = (lane&3) ^ ((lane>>3)&3) (linear gload_lds dest);
//   read slot = g4 ^ ((row>>1)&3)  -> exactly 8 lanes per 4-bank group
//   (b128 minimum), and read recovers global slot g4 = MFMA k-chunk.
// XCD-aware bijective grid swizzle (nwg % 8 == 0).
// EPI 0: bf16 out + bias[col]; 1: bf16 out*scale; 2: f32 out + X[idx];
// EPI 3: bf16 out to V^T layout [b][f=row][s], bias[row].
// =====================================================================

template<int EPI>
__global__ __launch_bounds__(512, 4) void gemm8_k(
    const short* __restrict__ A, const short* __restrict__ Bt,
    void* __restrict__ Cv, const float* __restrict__ X,
    int K, int lda, int ldb, int ldc,
    long long strA, long long strB, long long strC, long long strX, float scale) {
  // LDS (shorts): buffer i at i*12288: A (8192 shorts) then B (4096 shorts)
  __shared__ __align__(16) short Ls[36864];   // 72 KiB

  const int lane = threadIdx.x & 63;
  const int w = threadIdx.x >> 6;       // 0..7
  const int wm = w >> 1, wn = w & 1;
  const int l15 = lane & 15;
  const int g4 = lane >> 4;             // 0..3 = k-chunk
  // read-side swizzled 16B-slot (element offset within 32-elem row)
  const int swR = ((g4 ^ ((l15 >> 1) & 3)) << 3);
  const int arow = (wm * 64 + l15) * 32 + swR;   // + mi*512 (16 rows)
  const int brow = (wn * 64 + l15) * 32 + swR;   // + ni*512
  // stage-side source slot (dest stays linear): (lane&3) ^ ((lane>>3)&3)
  const int sg = (lane & 3) ^ ((lane >> 3) & 3);

  // ---- XCD-aware bijective block swizzle (requires nwg % 8 == 0) ----
  const int gx = gridDim.x, gy = gridDim.y;
  const int nwg = gx * gy * gridDim.z;
  int lid = blockIdx.x + gx * (blockIdx.y + gy * blockIdx.z);
  lid = (lid & 7) * (nwg >> 3) + (lid >> 3);
  const int bx = lid % gx;
  const int rem = lid / gx;
  const int by = rem % gy;
  const int bz = rem / gy;

  const int n0 = bx * 128;
  const int m0 = by * 256;
  const int nt = K >> 5;                // K-tiles (BK=32); always >= 16

  const long long ldaB = 2LL * lda, ldbB = 2LL * ldb;
  const long long ldaB16 = 16 * ldaB;

  // per-lane pre-swizzled staging source pointers (dest stays linear)
  const char* pA = (const char*)(A + (long long)bz * strA)
      + (long long)(m0 + w * 32 + (lane >> 2)) * ldaB + sg * 16;
  const char* pB = (const char*)(Bt + (long long)bz * strB)
      + (long long)(n0 + w * 16 + (lane >> 2)) * ldbB + sg * 16;

  short* dA = Ls + w * 1024;            // + buf*12288
  short* dB = Ls + 8192 + w * 512;      // + buf*12288

  f32x4 acc[4][4] = {};

  // ---- prologue: stage tiles 0,1,2 -> buffers 0,1,2 ----
#pragma unroll
  for (int i = 0; i < 3; ++i) {
    const char* qA = pA + i * 64;
    gload16(qA,           dA + i * 12288);
    gload16(qA + ldaB16,  dA + i * 12288 + 512);
    gload16(pB + i * 64,  dB + i * 12288);
  }
  asm volatile("s_waitcnt vmcnt(6)" ::: "memory");   // tile0 landed
  __builtin_amdgcn_s_barrier();

  int cur = 0;
  for (int t = 0; t < nt; ++t) {
    const int bufO = cur * 12288;
    bf16x8 aR[4], bR[4];
#pragma unroll
    for (int mi = 0; mi < 4; ++mi)
      aR[mi] = *(const bf16x8*)(Ls + bufO + arow + mi * 512);
#pragma unroll
    for (int ni = 0; ni < 4; ++ni)
      bR[ni] = *(const bf16x8*)(Ls + bufO + 8192 + brow + ni * 512);
    asm volatile("s_waitcnt lgkmcnt(0)" ::: "memory");  // my reads done
    __builtin_amdgcn_s_barrier();                       // all waves done w/ buf
    if (t + 3 < nt) {                                   // refill freed buffer
      const char* qA = pA + (t + 3) * 64;
      gload16(qA,          dA + bufO);
      gload16(qA + ldaB16, dA + bufO + 512);
      gload16(pB + (t + 3) * 64, dB + bufO);
    }
    __builtin_amdgcn_sched_barrier(0);
    __builtin_amdgcn_s_setprio(1);
#pragma unroll
    for (int mi = 0; mi < 4; ++mi)
#pragma unroll
      for (int ni = 0; ni < 4; ++ni)
        acc[mi][ni] = __builtin_amdgcn_mfma_f32_16x16x32_bf16(
            aR[mi], bR[ni], acc[mi][ni], 0, 0, 0);
    __builtin_amdgcn_s_setprio(0);
    if (t + 3 < nt)      asm volatile("s_waitcnt vmcnt(6)" ::: "memory");
    else if (t + 2 < nt) asm volatile("s_waitcnt vmcnt(3)" ::: "memory");
    else                 asm volatile("s_waitcnt vmcnt(0)" ::: "memory");
    __builtin_amdgcn_s_barrier();
    cur = (cur == 2) ? 0 : cur + 1;
  }

  // ---- epilogue ----
  const int rB = g4 * 4;
  if (EPI == 0) {
    short* C = (short*)Cv + (long long)bz * strC;
#pragma unroll
    for (int ni = 0; ni < 4; ++ni) {
      const int col = n0 + wn * 64 + ni * 16 + l15;
      const float bv = X[col];
#pragma unroll
      for (int mi = 0; mi < 4; ++mi)
#pragma unroll
        for (int r = 0; r < 4; ++r) {
          const int row = m0 + wm * 64 + mi * 16 + rB + r;
          C[(long long)row * ldc + col] = f2bf(acc[mi][ni][r] + bv);
        }
    }
  } else if (EPI == 1) {
    short* C = (short*)Cv + (long long)bz * strC;
#pragma unroll
    for (int ni = 0; ni < 4; ++ni) {
      const int col = n0 + wn * 64 + ni * 16 + l15;
#pragma unroll
      for (int mi = 0; mi < 4; ++mi)
#pragma unroll
        for (int r = 0; r < 4; ++r) {
          const int row = m0 + wm * 64 + mi * 16 + rB + r;
          C[(long long)row * ldc + col] = f2bf(acc[mi][ni][r] * scale);
        }
    }
  } else if (EPI == 2) {
    float* C = (float*)Cv + (long long)bz * strC;
    const float* Xb = X + (long long)bz * strX;
#pragma unroll
    for (int ni = 0; ni < 4; ++ni) {
      const int col = n0 + wn * 64 + ni * 16 + l15;
#pragma unroll
      for (int mi = 0; mi < 4; ++mi)
#pragma unroll
        for (int r = 0; r < 4; ++r) {
          const int row = m0 + wm * 64 + mi * 16 + rB + r;
          const long long idx = (long long)row * ldc + col;
          C[idx] = acc[mi][ni][r] + Xb[idx];
        }
    }
  } else {  // EPI == 3: C = V^T, [b][f=row][s], n = b*2048 + s
    short* C = (short*)Cv;
#pragma unroll
    for (int ni = 0; ni < 4; ++ni) {
      const int col = n0 + wn * 64 + ni * 16 + l15;
      const int b2 = col >> 11;
      const int s = col & 2047;
#pragma unroll
      for (int mi = 0; mi < 4; ++mi)
#pragma unroll
        for (int r = 0; r < 4; ++r) {
          const int row = m0 + wm * 64 + mi * 16 + rB + r;
          C[(long long)b2 * 2097152 + (long long)row * 2048 + s] =
              f2bf(acc[mi][ni][r] + X[row]);
        }
    }
  }
}

// ---------------- row softmax over 2048 (in-place, bf16) ----------------
__global__ __launch_bounds__(256) void softmax_k(short* __restrict__ P) {
  __shared__ float redm[4];
  __shared__ float reds[4];
  const long long row = blockIdx.x;
  short* p = P + row * 2048;
  const int t = threadIdx.x;
  const int w = t >> 6, lane = t & 63;
  bf16x8 v = *(const bf16x8*)(p + t * 8);
  float f[8];
  float mx = -3.0e38f;
#pragma unroll
  for (int j = 0; j < 8; ++j) { f[j] = bf2f(v[j]); mx = fmaxf(mx, f[j]); }
#pragma unroll
  for (int o = 32; o > 0; o >>= 1) mx = fmaxf(mx, __shfl_xor(mx, o));
  if (lane == 0) redm[w] = mx;
  __syncthreads();
  mx = fmaxf(fmaxf(redm[0], redm[1]), fmaxf(redm[2], redm[3]));
  float s = 0.f;
#pragma unroll
  for (int j = 0; j < 8; ++j) { f[j] = __expf(f[j] - mx); s += f[j]; }
#pragma unroll
  for (int o = 32; o > 0; o >>= 1) s += __shfl_xor(s, o);
  if (lane == 0) reds[w] = s;
  __syncthreads();
  s = reds[0] + reds[1] + reds[2] + reds[3];
  const float inv = 1.0f / (s + 1e-6f);
  bf16x8 o8;
#pragma unroll
  for (int j = 0; j < 8; ++j) o8[j] = f2bf(f[j] * inv);
  *(bf16x8*)(p + t * 8) = o8;
}

extern "C" void kernel_launch(void* const* d_in, const int* in_sizes, int n_in,
                              void* d_out, int out_size, void* d_ws, size_t ws_size,
                              hipStream_t stream) {
  const float* x  = (const float*)d_in[0];
  const float* y  = (const float*)d_in[1];
  const float* Wq = (const float*)d_in[2];
  const float* bq = (const float*)d_in[3];
  const float* Wk = (const float*)d_in[4];
  const float* bk = (const float*)d_in[5];
  const float* Wv = (const float*)d_in[6];
  const float* bv = (const float*)d_in[7];
  float* out = (float*)d_out;

  const long long SD  = 2048LL * 1024;
  const long long BSD = 16LL * SD;
  const long long SS  = 2048LL * 2048;

  char* ws = (char*)d_ws;
  short* xb  = (short*)ws;                   // 67.1 MB
  short* yb  = xb + BSD;                     // 67.1 MB
  short* Sl  = (short*)ws;                   // 134.2 MB (aliases xb+yb; written after they die)
  short* Qb  = (short*)(ws + 134217728);     // 67.1 MB
  short* Kb  = Qb + BSD;                     // 67.1 MB
  short* Vt  = Kb + BSD;                     // 67.1 MB  [b][d][s]
  short* Wqt = Vt + BSD;                     // 2 MB each
  short* Wkt = Wqt + 1024 * 1024;
  short* Wvt = Wkt + 1024 * 1024;

  // 1) convert x, y to bf16
  cvt_k<<<2048, 256, 0, stream>>>(x, xb, (int)(BSD / 4));
  cvt_k<<<2048, 256, 0, stream>>>(y, yb, (int)(BSD / 4));

  // 2) transpose+convert weights
  cvtT_k<<<dim3(32, 32), 256, 0, stream>>>(Wq, Wqt);
  cvtT_k<<<dim3(32, 32), 256, 0, stream>>>(Wk, Wkt);
  cvtT_k<<<dim3(32, 32), 256, 0, stream>>>(Wv, Wvt);

  // 3) Q = xb @ Wq + bq   (M=32768, N=1024, K=1024)
  gemm8_k<0><<<dim3(8, 128, 1), 512, 0, stream>>>(
      xb, Wqt, Qb, bq, 1024, 1024, 1024, 1024, 0, 0, 0, 0, 1.f);
  // 4) K = yb @ Wk + bk
  gemm8_k<0><<<dim3(8, 128, 1), 512, 0, stream>>>(
      yb, Wkt, Kb, bk, 1024, 1024, 1024, 1024, 0, 0, 0, 0, 1.f);
  // 5) V^T directly: A = Wv^T (M=1024=f), Bt = yb (N=32768) -> Vt[b][f][s]
  gemm8_k<3><<<dim3(256, 4, 1), 512, 0, stream>>>(
      Wvt, yb, Vt, bv, 1024, 1024, 1024, 0, 0, 0, 0, 0, 1.f);

  // 6) logits = Q @ K^T / 32  (batched 16x: M=N=2048, K=1024) -> bf16
  gemm8_k<1><<<dim3(16, 8, 16), 512, 0, stream>>>(
      Qb, Kb, Sl, nullptr, 1024, 1024, 1024, 2048, SD, SD, SS, 0, 0.03125f);

  // 7) softmax rows (32768 rows of 2048), in-place
  softmax_k<<<32768, 256, 0, stream>>>(Sl);

  // 8) out = P @ V + x  (batched 16x: M=2048, N=1024, K=2048) -> f32
  gemm8_k<2><<<dim3(8, 8, 16), 512, 0, stream>>>(
      Sl, Vt, out, x, 2048, 2048, 2048, 1024, SS, SD, SD, SD, 1.f);

  (void)in_sizes; (void)n_in; (void)out_size; (void)ws_size;
}